// Round 2
// baseline (309.639 us; speedup 1.0000x reference)
//
#include <hip/hip_runtime.h>

// ChannelAttention on MI355X (gfx950)
// B=128, HW=256 (=16x16), C=1024, S=32, EMB=256, IDF=256(==HW)
//
// out[b,p,c] = sum_s we[b,s,p] * softmax_s( sum_p' wc[b,p',c] * we[b,s,p'] )
// attn[b,c,s] = softmax probabilities
//
// d_out: out (128*256*1024 f32) then attn (128*1024*32 f32)
// d_ws : weT[b][p][s] (4 MB) — transposed projection so consumers read a
//        lane-uniform contiguous 128B row per p.
//
// R1: attn_kernel restructured for latency: 4 p-slices x 64 channels per
// block (grid 16x128 = 2048 blocks -> 8192 waves, ~16 waves/CU), unroll-8
// wc loads for ILP, LDS (padded stride 33) partial-logit reduction.

namespace {
constexpr int kB  = 128;
constexpr int kHW = 256;
constexpr int kC  = 1024;
constexpr int kS  = 32;
constexpr int kE  = 256;
}

__global__ __launch_bounds__(256) void we_proj_kernel(
    const float* __restrict__ emb, const float* __restrict__ K,
    const float* __restrict__ bias, float* __restrict__ weT) {
  const int b  = blockIdx.y;
  const int sq = blockIdx.x;           // 8 s-values per block
  const int p  = threadIdx.x;
  const float* embb = emb + (size_t)b * kS * kE + (size_t)sq * 8 * kE;

  float acc[8];
#pragma unroll
  for (int j = 0; j < 8; ++j) acc[j] = 0.f;

  for (int e = 0; e < kE; ++e) {
    const float k = K[e * kHW + p];          // lane-coalesced
#pragma unroll
    for (int j = 0; j < 8; ++j)              // lane-uniform -> scalar loads
      acc[j] = fmaf(embb[j * kE + e], k, acc[j]);
  }

  const float bv = bias[p];
  float4* dst = (float4*)(weT + ((size_t)b * kHW + p) * kS + sq * 8);
  dst[0] = make_float4(acc[0] + bv, acc[1] + bv, acc[2] + bv, acc[3] + bv);
  dst[1] = make_float4(acc[4] + bv, acc[5] + bv, acc[6] + bv, acc[7] + bv);
}

// grid (kC/64, kB) = (16,128); 256 threads = 4 slices x 64 channels.
// Wave w (= slice w) handles p in [64w, 64w+64) for channels c0..c0+63.
__global__ __launch_bounds__(256) void attn_kernel(
    const float* __restrict__ wc, const float* __restrict__ weT,
    float* __restrict__ out, float* __restrict__ attn_out) {
  const int b     = blockIdx.y;
  const int lane  = threadIdx.x & 63;
  const int slice = threadIdx.x >> 6;
  const int c     = blockIdx.x * 64 + lane;
  const int p0    = slice * 64;

  const float* wcb  = wc  + (size_t)b * kHW * kC;
  const float* weTb = weT + (size_t)b * kHW * kS;

  __shared__ float part[4][64][kS + 1];   // +1 pad: stride 33 -> conflict-free

  // ---- Phase A: partial logits over this slice's 64 p's ----
  float acc[kS];
#pragma unroll
  for (int s = 0; s < kS; ++s) acc[s] = 0.f;

#pragma unroll
  for (int pp = 0; pp < 64; pp += 8) {
    float w[8];
#pragma unroll
    for (int u = 0; u < 8; ++u)              // 8 coalesced loads in flight
      w[u] = wcb[(size_t)(p0 + pp + u) * kC + c];
#pragma unroll
    for (int u = 0; u < 8; ++u) {
      const float* wr = weTb + (size_t)(p0 + pp + u) * kS;  // uniform row
#pragma unroll
      for (int s = 0; s < kS; ++s)
        acc[s] = fmaf(wr[s], w[u], acc[s]);
    }
  }

  // ---- cross-slice reduction via LDS ----
#pragma unroll
  for (int s = 0; s < kS; ++s) part[slice][lane][s] = acc[s];
  __syncthreads();
#pragma unroll
  for (int sl = 0; sl < 4; ++sl) {
    if (sl != slice) {
#pragma unroll
      for (int s = 0; s < kS; ++s) acc[s] += part[sl][lane][s];
    }
  }

  // ---- softmax over s (per-thread, redundant across slices) ----
  float m = acc[0];
#pragma unroll
  for (int s = 1; s < kS; ++s) m = fmaxf(m, acc[s]);
  float sum = 0.f;
#pragma unroll
  for (int s = 0; s < kS; ++s) {
    acc[s] = __expf(acc[s] - m);
    sum += acc[s];
  }
  const float inv = 1.0f / sum;
#pragma unroll
  for (int s = 0; s < kS; ++s) acc[s] *= inv;

  // ---- attn store (slice 0 only; 128B contiguous per thread) ----
  if (slice == 0) {
    float4* ap = (float4*)(attn_out + ((size_t)b * kC + c) * kS);
#pragma unroll
    for (int s4 = 0; s4 < kS / 4; ++s4)
      ap[s4] = make_float4(acc[4 * s4], acc[4 * s4 + 1],
                           acc[4 * s4 + 2], acc[4 * s4 + 3]);
  }

  // ---- Phase B: out[p][c] for this slice's p-range ----
  float* outb = out + (size_t)b * kHW * kC;
#pragma unroll
  for (int pp = 0; pp < 64; pp += 8) {
#pragma unroll
    for (int u = 0; u < 8; ++u) {
      const int p = p0 + pp + u;
      const float* wr = weTb + (size_t)p * kS;   // uniform row
      float o = 0.f;
#pragma unroll
      for (int s = 0; s < kS; ++s)
        o = fmaf(wr[s], acc[s], o);
      outb[(size_t)p * kC + c] = o;              // coalesced store
    }
  }
}

extern "C" void kernel_launch(void* const* d_in, const int* in_sizes, int n_in,
                              void* d_out, int out_size, void* d_ws, size_t ws_size,
                              hipStream_t stream) {
  const float* wc   = (const float*)d_in[0];
  const float* emb  = (const float*)d_in[1];
  const float* K    = (const float*)d_in[2];
  const float* bias = (const float*)d_in[3];

  float* out  = (float*)d_out;
  float* attn = out + (size_t)kB * kHW * kC;
  float* weT  = (float*)d_ws;

  we_proj_kernel<<<dim3(4, kB), 256, 0, stream>>>(emb, K, bias, weT);
  attn_kernel<<<dim3(kC / 64, kB), 256, 0, stream>>>(wc, weT, out, attn);
}

// Round 3
// 211.884 us; speedup vs baseline: 1.4614x; 1.4614x over previous
//
#include <hip/hip_runtime.h>

// ChannelAttention on MI355X (gfx950)
// B=128, HW=256 (=16x16), C=1024, S=32, EMB=256, IDF=256(==HW)
//
// out[b,p,c] = sum_s we[b,s,p] * softmax_s( sum_p' wc[b,p',c] * we[b,s,p'] )
// attn[b,c,s] = softmax probabilities
//
// d_out: out (128*256*1024 f32) then attn (128*1024*32 f32)
// d_ws : weT[b][p][s] (4 MB) — transposed projection so consumers read a
//        lane-uniform contiguous 128B row per p.
//
// R2: R1 structure (4 p-slices x 64 ch, 2048 blocks, LDS partial-logit
// reduction) + readfirstlane(slice) so the weT row base is provably
// wave-uniform -> compiler emits s_load (scalar pipe) instead of per-lane
// broadcast global_loads (the R1 regression: 2048 extra VMEM instr/thread).

namespace {
constexpr int kB  = 128;
constexpr int kHW = 256;
constexpr int kC  = 1024;
constexpr int kS  = 32;
constexpr int kE  = 256;
}

__global__ __launch_bounds__(256) void we_proj_kernel(
    const float* __restrict__ emb, const float* __restrict__ K,
    const float* __restrict__ bias, float* __restrict__ weT) {
  const int b  = blockIdx.y;
  const int sq = blockIdx.x;           // 8 s-values per block
  const int p  = threadIdx.x;
  const float* embb = emb + (size_t)b * kS * kE + (size_t)sq * 8 * kE;

  float acc[8];
#pragma unroll
  for (int j = 0; j < 8; ++j) acc[j] = 0.f;

  for (int e = 0; e < kE; ++e) {
    const float k = K[e * kHW + p];          // lane-coalesced
#pragma unroll
    for (int j = 0; j < 8; ++j)              // lane-uniform -> scalar loads
      acc[j] = fmaf(embb[j * kE + e], k, acc[j]);
  }

  const float bv = bias[p];
  float4* dst = (float4*)(weT + ((size_t)b * kHW + p) * kS + sq * 8);
  dst[0] = make_float4(acc[0] + bv, acc[1] + bv, acc[2] + bv, acc[3] + bv);
  dst[1] = make_float4(acc[4] + bv, acc[5] + bv, acc[6] + bv, acc[7] + bv);
}

// grid (kC/64, kB) = (16,128); 256 threads = 4 slices x 64 channels.
__global__ __launch_bounds__(256) void attn_kernel(
    const float* __restrict__ wc, const float* __restrict__ weT,
    float* __restrict__ out, float* __restrict__ attn_out) {
  const int b     = blockIdx.y;
  const int lane  = threadIdx.x & 63;
  const int slice = threadIdx.x >> 6;
  const int c     = blockIdx.x * 64 + lane;
  // slice is uniform within a wave (blockDim=256, wave64) but the compiler
  // can't prove it: pin it to an SGPR so weT row addresses stay scalar.
  const int p0    = __builtin_amdgcn_readfirstlane(slice) * 64;

  const float* wcb  = wc  + (size_t)b * kHW * kC;
  const float* weTb = weT + (size_t)b * kHW * kS;

  __shared__ float part[4][64][kS + 1];   // stride 33 -> conflict-free

  // ---- Phase A: partial logits over this slice's 64 p's ----
  float acc[kS];
#pragma unroll
  for (int s = 0; s < kS; ++s) acc[s] = 0.f;

#pragma unroll
  for (int pp = 0; pp < 64; pp += 8) {
    float w[8];
#pragma unroll
    for (int u = 0; u < 8; ++u)              // 8 coalesced loads in flight
      w[u] = wcb[(size_t)(p0 + pp + u) * kC + c];
#pragma unroll
    for (int u = 0; u < 8; ++u) {
      const float* wr = weTb + (size_t)(p0 + pp + u) * kS;  // SGPR-based row
#pragma unroll
      for (int s = 0; s < kS; ++s)
        acc[s] = fmaf(wr[s], w[u], acc[s]);
    }
  }

  // ---- cross-slice reduction via LDS ----
  const int sl_w = threadIdx.x >> 6;       // vector index for the LDS write
#pragma unroll
  for (int s = 0; s < kS; ++s) part[sl_w][lane][s] = acc[s];
  __syncthreads();
#pragma unroll
  for (int sl = 0; sl < 4; ++sl) {
    if (sl != sl_w) {
#pragma unroll
      for (int s = 0; s < kS; ++s) acc[s] += part[sl][lane][s];
    }
  }

  // ---- softmax over s (per-thread, redundant across slices) ----
  float m = acc[0];
#pragma unroll
  for (int s = 1; s < kS; ++s) m = fmaxf(m, acc[s]);
  float sum = 0.f;
#pragma unroll
  for (int s = 0; s < kS; ++s) {
    acc[s] = __expf(acc[s] - m);
    sum += acc[s];
  }
  const float inv = 1.0f / sum;
#pragma unroll
  for (int s = 0; s < kS; ++s) acc[s] *= inv;

  // ---- attn store (slice 0 only; 128B contiguous per thread) ----
  if (sl_w == 0) {
    float4* ap = (float4*)(attn_out + ((size_t)b * kC + c) * kS);
#pragma unroll
    for (int s4 = 0; s4 < kS / 4; ++s4)
      ap[s4] = make_float4(acc[4 * s4], acc[4 * s4 + 1],
                           acc[4 * s4 + 2], acc[4 * s4 + 3]);
  }

  // ---- Phase B: out[p][c] for this slice's p-range ----
  float* outb = out + (size_t)b * kHW * kC;
#pragma unroll
  for (int pp = 0; pp < 64; pp += 8) {
#pragma unroll
    for (int u = 0; u < 8; ++u) {
      const int p = p0 + pp + u;
      const float* wr = weTb + (size_t)p * kS;   // SGPR-based row
      float o = 0.f;
#pragma unroll
      for (int s = 0; s < kS; ++s)
        o = fmaf(wr[s], acc[s], o);
      outb[(size_t)p * kC + c] = o;              // coalesced store
    }
  }
}

extern "C" void kernel_launch(void* const* d_in, const int* in_sizes, int n_in,
                              void* d_out, int out_size, void* d_ws, size_t ws_size,
                              hipStream_t stream) {
  const float* wc   = (const float*)d_in[0];
  const float* emb  = (const float*)d_in[1];
  const float* K    = (const float*)d_in[2];
  const float* bias = (const float*)d_in[3];

  float* out  = (float*)d_out;
  float* attn = out + (size_t)kB * kHW * kC;
  float* weT  = (float*)d_ws;

  we_proj_kernel<<<dim3(4, kB), 256, 0, stream>>>(emb, K, bias, weT);
  attn_kernel<<<dim3(kC / 64, kB), 256, 0, stream>>>(wc, weT, out, attn);
}